// Round 7
// baseline (776.440 us; speedup 1.0000x reference)
//
#include <hip/hip_runtime.h>
#include <hip/hip_bf16.h>

// VQ-VAE codebook lookup:
//  x: (8192, 16*64) f32, codebook: (16, 1024, 64) f32
//  out = [ cw_embed (8192,1024) f32 | one_hot (8192,16,1024) f32 ]
constexpr int NC    = 16;
constexpr int BS    = 1024;
constexpr int D     = 64;
constexpr int BATCH = 8192;
constexpr int BM    = 64;    // batch rows per workgroup
constexpr int BK    = 128;   // codebook entries per LDS chunk
constexpr int NCH   = BS / BK;

constexpr int XT_P = 68;     // LDS pitches (transposed tiles)
constexpr int CT_P = 132;

constexpr size_t EMBED_ELEMS = (size_t)BATCH * NC * D;   // 8388608

typedef float vf4 __attribute__((ext_vector_type(4)));

// ---------------------------------------------------------------------------
// Non-contractible fp32 ops: hipcc's -ffp-contract=fast fuses a*b+c into FMA;
// the asm barrier forces separate IEEE RN roundings, matching SSE numpy.
// ---------------------------------------------------------------------------
__device__ __forceinline__ float mulrn(float a, float b) {
  float r = a * b; asm volatile("" : "+v"(r)); return r;
}
__device__ __forceinline__ float addrn(float a, float b) {
  float r = a + b; asm volatile("" : "+v"(r)); return r;
}
__device__ __forceinline__ float subrn(float a, float b) {
  float r = a - b; asm volatile("" : "+v"(r)); return r;
}

// ---------------------------------------------------------------------------
// Bit-faithful numpy fp32 arithmetic models (pip wheel, baseline SSE3; einsum
// and pairwise_sum are compiled at baseline, not runtime-dispatched).
// ---------------------------------------------------------------------------

// np.einsum contig fp32 SSE: ONE 4-lane accumulator, 8-elem unroll, groups in
// ascending address order; final shuffle-reduce (S0+S1)+(S2+S3).
// x element d lives at x0[d*XSTR] (LDS column), c at c[d] (global row).
__device__ __forceinline__ float np_einsum_dot(const float* x0, const float* c) {
  float S0 = mulrn(x0[0 * XT_P], c[0]);
  float S1 = mulrn(x0[1 * XT_P], c[1]);
  float S2 = mulrn(x0[2 * XT_P], c[2]);
  float S3 = mulrn(x0[3 * XT_P], c[3]);
  #pragma unroll
  for (int t = 1; t < 16; ++t) {
    S0 = addrn(S0, mulrn(x0[(4 * t + 0) * XT_P], c[4 * t + 0]));
    S1 = addrn(S1, mulrn(x0[(4 * t + 1) * XT_P], c[4 * t + 1]));
    S2 = addrn(S2, mulrn(x0[(4 * t + 2) * XT_P], c[4 * t + 2]));
    S3 = addrn(S3, mulrn(x0[(4 * t + 3) * XT_P], c[4 * t + 3]));
  }
  return addrn(addrn(S0, S1), addrn(S2, S3));
}

// np.sum(v*v, -1), n=64 contiguous: np.multiply temp (one rounding/elem),
// then pairwise_sum npyv-SSE base case: 8 vector accumulators (r_v[j] =
// q[4v+j] + q[32+4v+j]), lanewise tree ((r0+r1)+(r2+r3))+((r4+r5)+(r6+r7)),
// then npyv_sum hadd tree (s0+s1)+(s2+s3).
template <int STRIDE>
__device__ __forceinline__ float np_sumsq(const float* p) {
  float s[4];
  #pragma unroll
  for (int j = 0; j < 4; ++j) {
    float r[8];
    #pragma unroll
    for (int v = 0; v < 8; ++v) {
      const float a0 = p[(4 * v + j) * STRIDE];
      const float a1 = p[(32 + 4 * v + j) * STRIDE];
      r[v] = addrn(mulrn(a0, a0), mulrn(a1, a1));
    }
    s[j] = addrn(addrn(addrn(r[0], r[1]), addrn(r[2], r[3])),
                 addrn(addrn(r[4], r[5]), addrn(r[6], r[7])));
  }
  return addrn(addrn(s[0], s[1]), addrn(s[2], s[3]));
}

// dist = fl( fl(x2 - fl(2*xc)) + c2 )
__device__ __forceinline__ float np_dist(const float* x0, const float* c, float x2n) {
  const float xc  = np_einsum_dot(x0, c);
  const float c2n = np_sumsq<1>(c);
  return addrn(subrn(x2n, mulrn(2.0f, xc)), c2n);
}

__global__ __launch_bounds__(256, 2) void vq_kernel(
    const float* __restrict__ x,
    const float* __restrict__ cb,
    float* __restrict__ out)
{
  __shared__ float Xs[D][XT_P];   // Xs[d][r]  : x tile transposed (exact bits)
  __shared__ float Cs[D][CT_P];   // Cs[d][cc] : codebook chunk transposed
  __shared__ float c2s[BK];
  __shared__ int   idxs[BM];

  const int tid = threadIdx.x;
  const int tx  = tid & 15;       // 16 col-groups
  const int ty  = tid >> 4;       // 16 row-groups (4 rows each)
  const int n   = blockIdx.y;
  const int rb  = blockIdx.x * BM;

  const float* __restrict__ cbn = cb + (size_t)n * BS * D;

  // ---- stage X tile transposed: Xs[d][r] = x[rb+r][n*64+d] ----
  {
    const float* xb = x + (size_t)rb * (NC * D) + (size_t)n * D;
    const int r = tid >> 2;          // 0..63
    const int b = tid & 3;           // 0..3
    #pragma unroll
    for (int i = 0; i < 4; ++i) {
      const int d4 = b * 4 + i * 16;
      float4 v = *reinterpret_cast<const float4*>(xb + (size_t)r * (NC * D) + d4);
      Xs[d4 + 0][r] = v.x;
      Xs[d4 + 1][r] = v.y;
      Xs[d4 + 2][r] = v.z;
      Xs[d4 + 3][r] = v.w;
    }
  }

  // lane-local running top-2 per row (fast fp32 FMA pass)
  float v1[4], v2[4];
  int   k1[4], k2[4];
  #pragma unroll
  for (int i = 0; i < 4; ++i) { v1[i] = 3.0e38f; v2[i] = 3.0e38f; k1[i] = 0; k2[i] = 0; }

  for (int ch = 0; ch < NCH; ++ch) {
    __syncthreads();                 // previous chunk fully consumed
    // ---- stage C chunk transposed: Cs[d][cc] = cb[n][ch*128+cc][d] ----
    {
      const float* cbase = cbn + (size_t)(ch * BK) * D;
      const int c0 = tid >> 2;
      const int b  = tid & 3;
      #pragma unroll
      for (int i = 0; i < 8; ++i) {
        const int cc = c0 + (i & 1) * 64;
        const int d4 = b * 4 + (i >> 1) * 16;
        float4 v = *reinterpret_cast<const float4*>(cbase + (size_t)cc * D + d4);
        Cs[d4 + 0][cc] = v.x;
        Cs[d4 + 1][cc] = v.y;
        Cs[d4 + 2][cc] = v.z;
        Cs[d4 + 3][cc] = v.w;
      }
    }
    __syncthreads();
    if (tid < BK) {                  // fast ||c||^2 for this chunk
      float s = 0.f;
      #pragma unroll
      for (int kk = 0; kk < D; ++kk) { float c = Cs[kk][tid]; s = fmaf(c, c, s); }
      c2s[tid] = s;
    }
    __syncthreads();

    // ---- 4 rows x 8 cols micro-tile dot products ----
    float acc[4][8];
    #pragma unroll
    for (int i = 0; i < 4; ++i)
      #pragma unroll
      for (int j = 0; j < 8; ++j) acc[i][j] = 0.f;

    #pragma unroll 8
    for (int kk = 0; kk < D; ++kk) {
      float4 xa = *reinterpret_cast<const float4*>(&Xs[kk][ty * 4]);
      float4 c0 = *reinterpret_cast<const float4*>(&Cs[kk][tx * 4]);
      float4 c1 = *reinterpret_cast<const float4*>(&Cs[kk][64 + tx * 4]);
      const float xs[4]  = {xa.x, xa.y, xa.z, xa.w};
      const float csv[8] = {c0.x, c0.y, c0.z, c0.w, c1.x, c1.y, c1.z, c1.w};
      #pragma unroll
      for (int i = 0; i < 4; ++i)
        #pragma unroll
        for (int j = 0; j < 8; ++j)
          acc[i][j] = fmaf(xs[i], csv[j], acc[i][j]);
    }

    // ---- update lane-local top-2 with this chunk's 8 candidates ----
    #pragma unroll
    for (int i = 0; i < 4; ++i) {
      #pragma unroll
      for (int j = 0; j < 8; ++j) {
        const int col = (j < 4) ? (tx * 4 + j) : (64 + tx * 4 + (j - 4));
        const float s = fmaf(-2.f, acc[i][j], c2s[col]);
        const int k = ch * BK + col;
        const bool lt1 = (s < v1[i]);
        const bool lt2 = (s < v2[i]);
        v2[i] = lt1 ? v1[i] : (lt2 ? s : v2[i]);
        k2[i] = lt1 ? k1[i] : (lt2 ? k : k2[i]);
        v1[i] = lt1 ? s : v1[i];
        k1[i] = lt1 ? k : k1[i];
      }
    }
  }

  // ---- per row: butterfly top-2 merge; np-refine 32 candidates if close ----
  #pragma unroll 1
  for (int i = 0; i < 4; ++i) {
    float a1 = v1[i], a2 = v2[i];
    int   b1 = k1[i], b2 = k2[i];
    #pragma unroll
    for (int m = 1; m <= 8; m <<= 1) {
      const float o1 = __shfl_xor(a1, m);
      const int   p1 = __shfl_xor(b1, m);
      const float o2 = __shfl_xor(a2, m);
      const int   p2 = __shfl_xor(b2, m);
      if (o1 < a1 || (o1 == a1 && p1 < b1)) {
        float n2; int q2;
        if (a1 < o2 || (a1 == o2 && b1 < p2)) { n2 = a1; q2 = b1; }
        else                                  { n2 = o2; q2 = p2; }
        a1 = o1; b1 = p1; a2 = n2; b2 = q2;
      } else {
        if (o1 < a2 || (o1 == a2 && p1 < b2)) { a2 = o1; b2 = p1; }
      }
    }
    // all 16 lanes hold the merged block top-2; row-uniform branch:
    int winner = b1;
    if (!(a2 - a1 > 0.05f)) {
      // ambiguous: decide among all 32 lane-kept candidates with the
      // bit-faithful numpy fp32 distance.
      const int r = ty * 4 + i;
      const float* x0 = &Xs[0][r];
      const float x2n = np_sumsq<XT_P>(x0);

      float bestv = np_dist(x0, cbn + (size_t)k1[i] * D, x2n);
      int   bestk = k1[i];
      const float d2 = np_dist(x0, cbn + (size_t)k2[i] * D, x2n);
      if (d2 < bestv || (d2 == bestv && k2[i] < bestk)) { bestv = d2; bestk = k2[i]; }

      #pragma unroll
      for (int m = 1; m <= 8; m <<= 1) {
        const float ov = __shfl_xor(bestv, m);
        const int   ok = __shfl_xor(bestk, m);
        if (ov < bestv || (ov == bestv && ok < bestk)) { bestv = ov; bestk = ok; }
      }
      winner = bestk;
    }
    if (tx == 0) idxs[ty * 4 + i] = winner;
  }
  __syncthreads();

  // ---- write cw_embed: out[rb+r][n*64+d] = cb[n][idx[r]][d] ----
  {
    const int r = tid >> 2;
    const int q = tid & 3;
    const int k = idxs[r];
    const float* src = cbn + (size_t)k * D + q * 16;
    float* dst = out + (size_t)(rb + r) * (NC * D) + (size_t)n * D + q * 16;
    #pragma unroll
    for (int j = 0; j < 4; ++j) {
      float4 v = *reinterpret_cast<const float4*>(src + 4 * j);
      vf4 w = {v.x, v.y, v.z, v.w};
      __builtin_nontemporal_store(w, reinterpret_cast<vf4*>(dst + 4 * j));
    }
  }

  // ---- write one-hot rows (zeros + the single 1 in one pass) ----
  {
    float* oh = out + EMBED_ELEMS;
    const int base = tid * 4;
    for (int r = 0; r < BM; ++r) {
      const int k = idxs[r];
      vf4 v;
      v.x = (k == base + 0) ? 1.f : 0.f;
      v.y = (k == base + 1) ? 1.f : 0.f;
      v.z = (k == base + 2) ? 1.f : 0.f;
      v.w = (k == base + 3) ? 1.f : 0.f;
      float* dst = oh + (size_t)(rb + r) * (NC * BS) + (size_t)n * BS + base;
      __builtin_nontemporal_store(v, reinterpret_cast<vf4*>(dst));
    }
  }
}

extern "C" void kernel_launch(void* const* d_in, const int* in_sizes, int n_in,
                              void* d_out, int out_size, void* d_ws, size_t ws_size,
                              hipStream_t stream) {
  const float* x  = (const float*)d_in[0];
  const float* cb = (const float*)d_in[1];
  float* out = (float*)d_out;
  dim3 grid(BATCH / BM, NC);
  vq_kernel<<<grid, dim3(256), 0, stream>>>(x, cb, out);
}

// Round 8
// 711.617 us; speedup vs baseline: 1.0911x; 1.0911x over previous
//
#include <hip/hip_runtime.h>
#include <hip/hip_bf16.h>

// VQ-VAE codebook lookup, MFMA bf16-split version:
//  x: (8192, 16*64) f32, codebook: (16, 1024, 64) f32
//  out = [ cw_embed (8192,1024) f32 | one_hot (8192,16,1024) f32 ]
// Fast path: dist filter via 3x mfma_f32_16x16x32_bf16 on (xh+xl)(ch+cl)
// split; ambiguous rows (gap<=0.08) decided by the round-7-verified
// bit-exact numpy fp32 emulation. d_ws holds pre-split codebook tables.
constexpr int NC    = 16;
constexpr int BS    = 1024;
constexpr int D     = 64;
constexpr int BATCH = 8192;
constexpr int BM    = 64;    // batch rows per workgroup
constexpr int CC    = 128;   // codebook entries per LDS chunk
constexpr int NCH   = BS / CC;
constexpr int PS    = 88;    // padded LDS row stride in shorts (16B-mult, ~2-way banks)

constexpr size_t EMBED_ELEMS = (size_t)BATCH * NC * D;   // 8388608
constexpr size_t CB_ELEMS    = (size_t)NC * BS * D;      // 1048576

typedef float vf4 __attribute__((ext_vector_type(4)));
typedef float floatx4 __attribute__((ext_vector_type(4)));
typedef short short8 __attribute__((ext_vector_type(8)));
typedef unsigned short u16;
typedef u16 u16x8 __attribute__((ext_vector_type(8)));

// ---------------------------------------------------------------------------
// Non-contractible fp32 ops (asm barrier defeats -ffp-contract=fast).
// VERIFIED bit-exact vs harness numpy reference in round 7. DO NOT REORDER.
// ---------------------------------------------------------------------------
__device__ __forceinline__ float mulrn(float a, float b) {
  float r = a * b; asm volatile("" : "+v"(r)); return r;
}
__device__ __forceinline__ float addrn(float a, float b) {
  float r = a + b; asm volatile("" : "+v"(r)); return r;
}
__device__ __forceinline__ float subrn(float a, float b) {
  float r = a - b; asm volatile("" : "+v"(r)); return r;
}

// np.einsum contig fp32 SSE: one 4-lane accumulator, ascending groups,
// final (S0+S1)+(S2+S3). Both pointers stride-1 (values bit-identical to
// the round-7 LDS-strided variant; only addressing changed).
__device__ __forceinline__ float np_einsum_dot(const float* x0, const float* c) {
  float S0 = mulrn(x0[0], c[0]);
  float S1 = mulrn(x0[1], c[1]);
  float S2 = mulrn(x0[2], c[2]);
  float S3 = mulrn(x0[3], c[3]);
  #pragma unroll
  for (int t = 1; t < 16; ++t) {
    S0 = addrn(S0, mulrn(x0[4 * t + 0], c[4 * t + 0]));
    S1 = addrn(S1, mulrn(x0[4 * t + 1], c[4 * t + 1]));
    S2 = addrn(S2, mulrn(x0[4 * t + 2], c[4 * t + 2]));
    S3 = addrn(S3, mulrn(x0[4 * t + 3], c[4 * t + 3]));
  }
  return addrn(addrn(S0, S1), addrn(S2, S3));
}

// np.sum(v*v, -1), n=64: multiply temp then pairwise npyv-SSE base case.
__device__ __forceinline__ float np_sumsq(const float* p) {
  float s[4];
  #pragma unroll
  for (int j = 0; j < 4; ++j) {
    float r[8];
    #pragma unroll
    for (int v = 0; v < 8; ++v) {
      const float a0 = p[4 * v + j];
      const float a1 = p[32 + 4 * v + j];
      r[v] = addrn(mulrn(a0, a0), mulrn(a1, a1));
    }
    s[j] = addrn(addrn(addrn(r[0], r[1]), addrn(r[2], r[3])),
                 addrn(addrn(r[4], r[5]), addrn(r[6], r[7])));
  }
  return addrn(addrn(s[0], s[1]), addrn(s[2], s[3]));
}

__device__ __forceinline__ float np_dist(const float* x0, const float* c, float x2n) {
  const float xc  = np_einsum_dot(x0, c);
  const float c2n = np_sumsq(c);
  return addrn(subrn(x2n, mulrn(2.0f, xc)), c2n);
}

// bf16 round-to-nearest-even
__device__ __forceinline__ u16 f2bf(float f) {
  unsigned u = __float_as_uint(f);
  return (u16)((u + 0x7FFFu + ((u >> 16) & 1u)) >> 16);
}
__device__ __forceinline__ float bf2f(u16 h) {
  return __uint_as_float(((unsigned)h) << 16);
}

// ---------------------------------------------------------------------------
// Pre-kernel: split codebook into bf16 hi/lo tables + fp32 c2 into d_ws.
// ws layout: [hi: 2MB][lo: 2MB][c2: 64KB]
// ---------------------------------------------------------------------------
__global__ __launch_bounds__(256) void split_kernel(
    const float* __restrict__ cb, u16* __restrict__ wh, u16* __restrict__ wl,
    float* __restrict__ wc2)
{
  const int t    = blockIdx.x * 256 + threadIdx.x;   // 0..65535
  const int cand = t >> 2;                           // global cand row 0..16383
  const int part = t & 3;                            // 16-dim quarter
  const float* src = cb + (size_t)cand * D + part * 16;
  u16 hh[16], ll[16];
  float ss = 0.f;
  #pragma unroll
  for (int i = 0; i < 4; ++i) {
    float4 v = *reinterpret_cast<const float4*>(src + 4 * i);
    const float fv[4] = {v.x, v.y, v.z, v.w};
    #pragma unroll
    for (int j = 0; j < 4; ++j) {
      const float f = fv[j];
      const u16 h = f2bf(f);
      const float lo = f - bf2f(h);
      hh[4 * i + j] = h;
      ll[4 * i + j] = f2bf(lo);
      ss = fmaf(f, f, ss);
    }
  }
  u16* dh = wh + (size_t)cand * D + part * 16;
  u16* dl = wl + (size_t)cand * D + part * 16;
  *reinterpret_cast<u16x8*>(dh)     = *reinterpret_cast<u16x8*>(&hh[0]);
  *reinterpret_cast<u16x8*>(dh + 8) = *reinterpret_cast<u16x8*>(&hh[8]);
  *reinterpret_cast<u16x8*>(dl)     = *reinterpret_cast<u16x8*>(&ll[0]);
  *reinterpret_cast<u16x8*>(dl + 8) = *reinterpret_cast<u16x8*>(&ll[8]);
  ss += __shfl_xor(ss, 1);
  ss += __shfl_xor(ss, 2);
  if (part == 0) wc2[cand] = ss;
}

// ---------------------------------------------------------------------------
// Main kernel
// ---------------------------------------------------------------------------
__global__ __launch_bounds__(256, 2) void vq_kernel(
    const float* __restrict__ x,
    const float* __restrict__ cb,
    const u16* __restrict__ wh, const u16* __restrict__ wl,
    const float* __restrict__ wc2,
    float* __restrict__ out)
{
  __shared__ u16   XhS[BM * PS];   // x hi tile  [64][88]
  __shared__ u16   XlS[BM * PS];   // x lo tile
  __shared__ u16   ChS[CC * PS];   // cand hi chunk [128][88]
  __shared__ u16   ClS[CC * PS];   // cand lo chunk
  __shared__ float c2s[BS];
  __shared__ int   idxs[BM];

  const int tid  = threadIdx.x;
  const int wave = tid >> 6;
  const int lane = tid & 63;
  const int g    = lane >> 4;      // k-group / output row-quad
  const int tx   = lane & 15;      // operand row index / output col
  const int n    = blockIdx.y;
  const int rb   = blockIdx.x * BM;

  const float* __restrict__ cbn = cb + (size_t)n * BS * D;
  const u16*   __restrict__ whn = wh + (size_t)n * BS * D;
  const u16*   __restrict__ wln = wl + (size_t)n * BS * D;

  // ---- stage c2 table for this n ----
  *reinterpret_cast<float4*>(&c2s[tid * 4]) =
      *reinterpret_cast<const float4*>(wc2 + (size_t)n * BS + tid * 4);

  // ---- stage X tile, split to bf16 hi/lo: rows rb..rb+63, dims n*64.. ----
  {
    const int r = tid >> 2;          // 0..63
    const int b = tid & 3;           // 16-dim quarter
    const float* xr = x + (size_t)(rb + r) * (NC * D) + (size_t)n * D + b * 16;
    u16 hh[16], ll[16];
    #pragma unroll
    for (int i = 0; i < 4; ++i) {
      float4 v = *reinterpret_cast<const float4*>(xr + 4 * i);
      const float fv[4] = {v.x, v.y, v.z, v.w};
      #pragma unroll
      for (int j = 0; j < 4; ++j) {
        const float f = fv[j];
        const u16 h = f2bf(f);
        hh[4 * i + j] = h;
        ll[4 * i + j] = f2bf(f - bf2f(h));
      }
    }
    u16* dh = &XhS[r * PS + b * 16];
    u16* dl = &XlS[r * PS + b * 16];
    *reinterpret_cast<u16x8*>(dh)     = *reinterpret_cast<u16x8*>(&hh[0]);
    *reinterpret_cast<u16x8*>(dh + 8) = *reinterpret_cast<u16x8*>(&hh[8]);
    *reinterpret_cast<u16x8*>(dl)     = *reinterpret_cast<u16x8*>(&ll[0]);
    *reinterpret_cast<u16x8*>(dl + 8) = *reinterpret_cast<u16x8*>(&ll[8]);
  }
  __syncthreads();

  // ---- A-frags: wave's 16 rows (wr+tx), k-contig 8 at g*8 (+32 per kstep) ----
  const int wr = wave * 16;
  short8 ah0 = *reinterpret_cast<const short8*>(&XhS[(wr + tx) * PS + g * 8]);
  short8 ah1 = *reinterpret_cast<const short8*>(&XhS[(wr + tx) * PS + g * 8 + 32]);
  short8 al0 = *reinterpret_cast<const short8*>(&XlS[(wr + tx) * PS + g * 8]);
  short8 al1 = *reinterpret_cast<const short8*>(&XlS[(wr + tx) * PS + g * 8 + 32]);

  // lane-local top-2 per output-row slot (rows wr + g*4 + reg)
  float v1[4], v2[4];
  int   k1[4], k2[4];
  #pragma unroll
  for (int i = 0; i < 4; ++i) { v1[i] = 3.0e38f; v2[i] = 3.0e38f; k1[i] = 0; k2[i] = 0; }

  for (int ch = 0; ch < NCH; ++ch) {
    __syncthreads();                 // previous chunk fully consumed
    // ---- stage C chunk (bf16 pre-split from ws) ----
    {
      const int cl = tid >> 1;       // 0..127 local cand
      const int hf = tid & 1;        // 32-dim half
      const size_t gofs = (size_t)(ch * CC + cl) * D + hf * 32;
      const u16* sh = whn + gofs;
      const u16* sl = wln + gofs;
      u16* dh = &ChS[cl * PS + hf * 32];
      u16* dl = &ClS[cl * PS + hf * 32];
      #pragma unroll
      for (int j = 0; j < 4; ++j) {
        *reinterpret_cast<u16x8*>(dh + 8 * j) = *reinterpret_cast<const u16x8*>(sh + 8 * j);
        *reinterpret_cast<u16x8*>(dl + 8 * j) = *reinterpret_cast<const u16x8*>(sl + 8 * j);
      }
    }
    __syncthreads();

    // ---- 8 cand-tiles of 16: 6 MFMAs each (split product), top-2 update ----
    #pragma unroll
    for (int t = 0; t < 8; ++t) {
      const int cbase = t * 16;
      const short8 bh0 = *reinterpret_cast<const short8*>(&ChS[(cbase + tx) * PS + g * 8]);
      const short8 bh1 = *reinterpret_cast<const short8*>(&ChS[(cbase + tx) * PS + g * 8 + 32]);
      const short8 bl0 = *reinterpret_cast<const short8*>(&ClS[(cbase + tx) * PS + g * 8]);
      const short8 bl1 = *reinterpret_cast<const short8*>(&ClS[(cbase + tx) * PS + g * 8 + 32]);

      floatx4 acc = {0.f, 0.f, 0.f, 0.f};
      acc = __builtin_amdgcn_mfma_f32_16x16x32_bf16(ah0, bh0, acc, 0, 0, 0);
      acc = __builtin_amdgcn_mfma_f32_16x16x32_bf16(ah1, bh1, acc, 0, 0, 0);
      acc = __builtin_amdgcn_mfma_f32_16x16x32_bf16(ah0, bl0, acc, 0, 0, 0);
      acc = __builtin_amdgcn_mfma_f32_16x16x32_bf16(ah1, bl1, acc, 0, 0, 0);
      acc = __builtin_amdgcn_mfma_f32_16x16x32_bf16(al0, bh0, acc, 0, 0, 0);
      acc = __builtin_amdgcn_mfma_f32_16x16x32_bf16(al1, bh1, acc, 0, 0, 0);

      const int  k   = ch * CC + cbase + tx;   // global cand index (col = tx)
      const float c2v = c2s[k];
      #pragma unroll
      for (int reg = 0; reg < 4; ++reg) {
        const float s = fmaf(-2.f, acc[reg], c2v);
        const bool lt1 = (s < v1[reg]);
        const bool lt2 = (s < v2[reg]);
        v2[reg] = lt1 ? v1[reg] : (lt2 ? s : v2[reg]);
        k2[reg] = lt1 ? k1[reg] : (lt2 ? k : k2[reg]);
        v1[reg] = lt1 ? s : v1[reg];
        k1[reg] = lt1 ? k : k1[reg];
      }
    }
  }

  // ---- per output row: merge top-2 across the 16 col-lanes; refine if close ----
  #pragma unroll 1
  for (int reg = 0; reg < 4; ++reg) {
    float a1 = v1[reg], a2 = v2[reg];
    int   b1 = k1[reg], b2 = k2[reg];
    #pragma unroll
    for (int m = 1; m <= 8; m <<= 1) {
      const float o1 = __shfl_xor(a1, m);
      const int   p1 = __shfl_xor(b1, m);
      const float o2 = __shfl_xor(a2, m);
      const int   p2 = __shfl_xor(b2, m);
      if (o1 < a1 || (o1 == a1 && p1 < b1)) {
        float n2; int q2;
        if (a1 < o2 || (a1 == o2 && b1 < p2)) { n2 = a1; q2 = b1; }
        else                                  { n2 = o2; q2 = p2; }
        a1 = o1; b1 = p1; a2 = n2; b2 = q2;
      } else {
        if (o1 < a2 || (o1 == a2 && p1 < b2)) { a2 = o1; b2 = p1; }
      }
    }
    const int row_local = wr + g * 4 + reg;
    int winner = b1;
    if (!(a2 - a1 > 0.08f)) {
      // ambiguous under bf16-split noise: np-exact decide among the 32
      // lane-kept candidates (each lane evaluates its own pre-merge top-2).
      const float* xrow = x + (size_t)(rb + row_local) * (NC * D) + (size_t)n * D;
      const float x2n = np_sumsq(xrow);
      float bestv = np_dist(xrow, cbn + (size_t)k1[reg] * D, x2n);
      int   bestk = k1[reg];
      const float dd = np_dist(xrow, cbn + (size_t)k2[reg] * D, x2n);
      if (dd < bestv || (dd == bestv && k2[reg] < bestk)) { bestv = dd; bestk = k2[reg]; }
      #pragma unroll
      for (int m = 1; m <= 8; m <<= 1) {
        const float ov = __shfl_xor(bestv, m);
        const int   ok = __shfl_xor(bestk, m);
        if (ov < bestv || (ov == bestv && ok < bestk)) { bestv = ov; bestk = ok; }
      }
      winner = bestk;
    }
    if (tx == 0) idxs[row_local] = winner;
  }
  __syncthreads();

  // ---- write cw_embed: out[rb+r][n*64+d] = cb[n][idx[r]][d] ----
  {
    const int r = tid >> 2;
    const int q = tid & 3;
    const int k = idxs[r];
    const float* src = cbn + (size_t)k * D + q * 16;
    float* dst = out + (size_t)(rb + r) * (NC * D) + (size_t)n * D + q * 16;
    #pragma unroll
    for (int j = 0; j < 4; ++j) {
      float4 v = *reinterpret_cast<const float4*>(src + 4 * j);
      vf4 w = {v.x, v.y, v.z, v.w};
      __builtin_nontemporal_store(w, reinterpret_cast<vf4*>(dst + 4 * j));
    }
  }

  // ---- write one-hot rows (zeros + the single 1 in one pass) ----
  {
    float* oh = out + EMBED_ELEMS;
    const int base = tid * 4;
    for (int r = 0; r < BM; ++r) {
      const int k = idxs[r];
      vf4 v;
      v.x = (k == base + 0) ? 1.f : 0.f;
      v.y = (k == base + 1) ? 1.f : 0.f;
      v.z = (k == base + 2) ? 1.f : 0.f;
      v.w = (k == base + 3) ? 1.f : 0.f;
      float* dst = oh + (size_t)(rb + r) * (NC * BS) + (size_t)n * BS + base;
      __builtin_nontemporal_store(v, reinterpret_cast<vf4*>(dst));
    }
  }
}

extern "C" void kernel_launch(void* const* d_in, const int* in_sizes, int n_in,
                              void* d_out, int out_size, void* d_ws, size_t ws_size,
                              hipStream_t stream) {
  const float* x  = (const float*)d_in[0];
  const float* cb = (const float*)d_in[1];
  float* out = (float*)d_out;

  u16*   wh  = (u16*)d_ws;                    // 2 MB
  u16*   wl  = wh + CB_ELEMS;                 // 2 MB
  float* wc2 = (float*)(wl + CB_ELEMS);       // 64 KB

  split_kernel<<<dim3(256), dim3(256), 0, stream>>>(cb, wh, wl, wc2);
  dim3 grid(BATCH / BM, NC);
  vq_kernel<<<grid, dim3(256), 0, stream>>>(x, cb, wh, wl, wc2, out);
}